// Round 1
// baseline (445.889 us; speedup 1.0000x reference)
//
#include <hip/hip_runtime.h>
#include <math.h>

#define B_ 4
#define N_ 2048
#define C_ 64
#define H_ 16
#define D_ 64
#define HID 1024

// fold attention scale (1/8) and log2(e) into Q so softmax uses exp2 directly
#define QSCALE 0.18033688011112042f  // 0.125 * 1.4426950408889634

typedef short bf16x8 __attribute__((ext_vector_type(8)));
typedef unsigned short u16x8 __attribute__((ext_vector_type(8)));
typedef float f32x4 __attribute__((ext_vector_type(4)));

#define MFMA(a, b, c) __builtin_amdgcn_mfma_f32_16x16x32_bf16((a), (b), (c), 0, 0, 0)

static __device__ __forceinline__ unsigned short f2bf(float f) {
  unsigned u = __float_as_uint(f);
  u += 0x7FFFu + ((u >> 16) & 1u);   // round-to-nearest-even
  return (unsigned short)(u >> 16);
}
static __device__ __forceinline__ float bf2f(unsigned short h) {
  return __uint_as_float((unsigned)h << 16);
}

// ---------------------------------------------------------------------------
// Kernel 1: QKV projection (K=64) + split into bf16 hi/lo arrays [B][H][N][D]
// grid (24 col-tiles of 128, 256 token-tiles of 32), block 256
// ---------------------------------------------------------------------------
__global__ __launch_bounds__(256) void qkv_kernel(
    const float* __restrict__ X, const float* __restrict__ W,
    const float* __restrict__ bias,
    unsigned short* __restrict__ Qhi, unsigned short* __restrict__ Qlo,
    unsigned short* __restrict__ Khi, unsigned short* __restrict__ Klo,
    unsigned short* __restrict__ Vhi, unsigned short* __restrict__ Vlo) {
  __shared__ float Xl[32][68];     // 32 tokens x 64 feats, +4 pad
  __shared__ float Wl[64][132];    // 64 feats x 128 cols, +4 pad
  const int t = threadIdx.x;
  const int ct = blockIdx.x;       // col tile: cols ct*128 .. +127 (within one of q/k/v)
  const int tt = blockIdx.y;       // token tile: tokens tt*32 .. +31

#pragma unroll
  for (int i = 0; i < 2; ++i) {
    int idx = t + 256 * i;
    int tok = idx >> 4, f4 = (idx & 15) * 4;
    *(f32x4*)&Xl[tok][f4] = *(const f32x4*)&X[(size_t)(tt * 32 + tok) * 64 + f4];
  }
#pragma unroll
  for (int i = 0; i < 8; ++i) {
    int idx = t + 256 * i;
    int c = idx >> 5, f4 = (idx & 31) * 4;
    *(f32x4*)&Wl[c][f4] = *(const f32x4*)&W[(size_t)c * 3072 + ct * 128 + f4];
  }
  __syncthreads();

  const int tokg = t >> 5;   // 8 groups of 4 tokens
  const int colg = t & 31;   // 32 groups of 4 cols
  f32x4 acc[4];
#pragma unroll
  for (int i = 0; i < 4; ++i) acc[i] = (f32x4){0.f, 0.f, 0.f, 0.f};

#pragma unroll 4
  for (int c4 = 0; c4 < 64; c4 += 4) {
    f32x4 xr[4], wr[4];
#pragma unroll
    for (int i = 0; i < 4; ++i) xr[i] = *(const f32x4*)&Xl[tokg * 4 + i][c4];
#pragma unroll
    for (int j = 0; j < 4; ++j) wr[j] = *(const f32x4*)&Wl[c4 + j][colg * 4];
#pragma unroll
    for (int j = 0; j < 4; ++j)
#pragma unroll
      for (int i = 0; i < 4; ++i) acc[i] += xr[i][j] * wr[j];
  }

  const int s = (ct * 128) >> 10;  // 0=q 1=k 2=v (uniform per block)
  unsigned short* hiA = (s == 0) ? Qhi : ((s == 1) ? Khi : Vhi);
  unsigned short* loA = (s == 0) ? Qlo : ((s == 1) ? Klo : Vlo);
  const float scale = (s == 0) ? QSCALE : 1.0f;
  const f32x4 bia = *(const f32x4*)&bias[ct * 128 + colg * 4];

#pragma unroll
  for (int i = 0; i < 4; ++i) {
    int token = tt * 32 + tokg * 4 + i;
    int bb = token >> 11, n = token & 2047;
#pragma unroll
    for (int cc = 0; cc < 4; ++cc) {
      int o = ct * 128 + colg * 4 + cc;
      int hh = (o >> 6) & 15, d = o & 63;
      float v = (acc[i][cc] + bia[cc]) * scale;
      unsigned short hi = f2bf(v);
      unsigned short lo = f2bf(v - bf2f(hi));
      size_t dst = ((size_t)(bb * H_ + hh) * N_ + n) * D_ + d;
      hiA[dst] = hi;
      loA[dst] = lo;
    }
  }
}

// ---------------------------------------------------------------------------
// Kernel 2: flash attention, bf16 MFMA 16x16x32 with hi/lo error compensation.
// grid (16 q-tiles of 128, 16 heads, 4 batch), block 256 (4 waves x 32 q-rows)
// K-tile = 64 keys. LDS rows padded to 72 bf16 (144B) for conflict-free b128.
// ---------------------------------------------------------------------------
__global__ __launch_bounds__(256, 2) void attn_kernel(
    const unsigned short* __restrict__ Qhi, const unsigned short* __restrict__ Qlo,
    const unsigned short* __restrict__ Khi, const unsigned short* __restrict__ Klo,
    const unsigned short* __restrict__ Vhi, const unsigned short* __restrict__ Vlo,
    float* __restrict__ ctx) {
  __shared__ unsigned short sKhi[64][72];
  __shared__ unsigned short sKlo[64][72];
  __shared__ unsigned short sVthi[64][72];  // transposed: [d][key]
  __shared__ unsigned short sVtlo[64][72];
  __shared__ unsigned short sP[128][72];    // P, wave-private row ranges

  const int tid = threadIdx.x;
  const int wave = tid >> 6, lane = tid & 63;
  const int lid = lane & 15, quad = lane >> 4;
  const int b = blockIdx.z, h = blockIdx.y, qt = blockIdx.x;
  const size_t base = (size_t)(b * H_ + h) * N_ * D_;
  const int q0 = qt * 128;

  // Q fragments (A-layout: m=lane&15, k=quad*8+j), held in regs all kernel
  bf16x8 qh[2][2], ql[2][2];
#pragma unroll
  for (int m2 = 0; m2 < 2; ++m2) {
    int row = q0 + wave * 32 + m2 * 16 + lid;
    const unsigned short* qph = Qhi + base + (size_t)row * D_;
    const unsigned short* qpl = Qlo + base + (size_t)row * D_;
#pragma unroll
    for (int kc = 0; kc < 2; ++kc) {
      qh[m2][kc] = *(const bf16x8*)(qph + kc * 32 + quad * 8);
      ql[m2][kc] = *(const bf16x8*)(qpl + kc * 32 + quad * 8);
    }
  }

  float m_i[2][4], l_i[2][4];
  f32x4 o[2][4];
#pragma unroll
  for (int m2 = 0; m2 < 2; ++m2)
#pragma unroll
    for (int r = 0; r < 4; ++r) {
      m_i[m2][r] = -1e30f;
      l_i[m2][r] = 0.f;
    }
#pragma unroll
  for (int m2 = 0; m2 < 2; ++m2)
#pragma unroll
    for (int dnt = 0; dnt < 4; ++dnt) o[m2][dnt] = (f32x4){0.f, 0.f, 0.f, 0.f};

  for (int kt = 0; kt < N_ / 64; ++kt) {
    __syncthreads();  // previous iteration's LDS reads complete
    {
      // stage K tile [64 keys][64 d], coalesced 16B loads, b128 LDS writes
      const size_t src0 = base + (size_t)(kt * 64) * D_;
      int krow = tid >> 3, kdc = (tid & 7) * 8;
#pragma unroll
      for (int pass = 0; pass < 2; ++pass) {
        int r = krow + pass * 32;
        *(uint4*)&sKhi[r][kdc] = *(const uint4*)(Khi + src0 + (size_t)r * D_ + kdc);
        *(uint4*)&sKlo[r][kdc] = *(const uint4*)(Klo + src0 + (size_t)r * D_ + kdc);
      }
      // stage V transposed: thread owns one key, 8 d-values; scatter b16 writes
      int key = tid & 63;
#pragma unroll
      for (int pass = 0; pass < 2; ++pass) {
        int dc2 = (tid >> 6) + pass * 4;
        u16x8 v1 = *(const u16x8*)(Vhi + src0 + (size_t)key * D_ + dc2 * 8);
        u16x8 v2 = *(const u16x8*)(Vlo + src0 + (size_t)key * D_ + dc2 * 8);
#pragma unroll
        for (int j = 0; j < 8; ++j) {
          sVthi[dc2 * 8 + j][key] = v1[j];
          sVtlo[dc2 * 8 + j][key] = v2[j];
        }
      }
    }
    __syncthreads();

    // S = Q Kt (3-term hi/lo) + online softmax + P to LDS
#pragma unroll
    for (int m2 = 0; m2 < 2; ++m2) {
      f32x4 sc[4];
#pragma unroll
      for (int nt = 0; nt < 4; ++nt) {
        f32x4 c = (f32x4){0.f, 0.f, 0.f, 0.f};
#pragma unroll
        for (int kc = 0; kc < 2; ++kc) {
          bf16x8 bh_ = *(const bf16x8*)&sKhi[nt * 16 + lid][kc * 32 + quad * 8];
          bf16x8 bl_ = *(const bf16x8*)&sKlo[nt * 16 + lid][kc * 32 + quad * 8];
          c = MFMA(qh[m2][kc], bh_, c);
          c = MFMA(qh[m2][kc], bl_, c);
          c = MFMA(ql[m2][kc], bh_, c);
        }
        sc[nt] = c;
      }
      // row max over 64 keys (cols live across the 16 lid lanes)
      float mx[4];
#pragma unroll
      for (int r = 0; r < 4; ++r)
        mx[r] = fmaxf(fmaxf(sc[0][r], sc[1][r]), fmaxf(sc[2][r], sc[3][r]));
#pragma unroll
      for (int mask = 1; mask < 16; mask <<= 1)
#pragma unroll
        for (int r = 0; r < 4; ++r) mx[r] = fmaxf(mx[r], __shfl_xor(mx[r], mask));

      float al[4];
#pragma unroll
      for (int r = 0; r < 4; ++r) {
        float mn = fmaxf(m_i[m2][r], mx[r]);
        al[r] = __builtin_amdgcn_exp2f(m_i[m2][r] - mn);
        m_i[m2][r] = mn;
      }
      float rs[4] = {0.f, 0.f, 0.f, 0.f};
#pragma unroll
      for (int nt = 0; nt < 4; ++nt)
#pragma unroll
        for (int r = 0; r < 4; ++r) {
          float p = __builtin_amdgcn_exp2f(sc[nt][r] - m_i[m2][r]);
          sc[nt][r] = p;
          rs[r] += p;
        }
#pragma unroll
      for (int mask = 1; mask < 16; mask <<= 1)
#pragma unroll
        for (int r = 0; r < 4; ++r) rs[r] += __shfl_xor(rs[r], mask);
#pragma unroll
      for (int r = 0; r < 4; ++r) l_i[m2][r] = l_i[m2][r] * al[r] + rs[r];
      // rescale O
#pragma unroll
      for (int dnt = 0; dnt < 4; ++dnt)
#pragma unroll
        for (int r = 0; r < 4; ++r) o[m2][dnt][r] *= al[r];
      // P -> LDS (C-layout scatter; wave-private rows, no barrier needed)
#pragma unroll
      for (int nt = 0; nt < 4; ++nt)
#pragma unroll
        for (int r = 0; r < 4; ++r)
          sP[wave * 32 + m2 * 16 + quad * 4 + r][nt * 16 + lid] = f2bf(sc[nt][r]);
    }

    // O += P V (2-term V hi/lo)
#pragma unroll
    for (int m2 = 0; m2 < 2; ++m2) {
      bf16x8 pa[2];
#pragma unroll
      for (int kc = 0; kc < 2; ++kc)
        pa[kc] = *(const bf16x8*)&sP[wave * 32 + m2 * 16 + lid][kc * 32 + quad * 8];
#pragma unroll
      for (int dnt = 0; dnt < 4; ++dnt) {
        f32x4 c = o[m2][dnt];
#pragma unroll
        for (int kc = 0; kc < 2; ++kc) {
          bf16x8 vh = *(const bf16x8*)&sVthi[dnt * 16 + lid][kc * 32 + quad * 8];
          bf16x8 vl = *(const bf16x8*)&sVtlo[dnt * 16 + lid][kc * 32 + quad * 8];
          c = MFMA(pa[kc], vh, c);
          c = MFMA(pa[kc], vl, c);
        }
        o[m2][dnt] = c;
      }
    }
  }

  // epilogue: normalize and write ctx[B*N][HID] at hidden offset h*64
#pragma unroll
  for (int m2 = 0; m2 < 2; ++m2)
#pragma unroll
    for (int r = 0; r < 4; ++r) {
      float inv = 1.0f / l_i[m2][r];
      int row = q0 + wave * 32 + m2 * 16 + quad * 4 + r;
      size_t tok = (size_t)b * N_ + row;
#pragma unroll
      for (int dnt = 0; dnt < 4; ++dnt)
        ctx[tok * HID + h * 64 + dnt * 16 + lid] = o[m2][dnt][r] * inv;
    }
}

// ---------------------------------------------------------------------------
// Kernel 3: out projection (K=1024) + exact GELU. grid 512 (16 tokens/block)
// ---------------------------------------------------------------------------
__global__ __launch_bounds__(256) void out_kernel(
    const float* __restrict__ ctx, const float* __restrict__ W2,
    const float* __restrict__ b2, float* __restrict__ out) {
  __shared__ float Cl[16][132];
  __shared__ float Wl[128][68];
  const int t = threadIdx.x;
  const int tt = blockIdx.x;
  const int tokg = t >> 5;  // 8 groups of 2 tokens
  const int colg = t & 31;  // 32 groups of 2 cols
  float acc[2][2] = {{0.f, 0.f}, {0.f, 0.f}};

  for (int kt = 0; kt < 8; ++kt) {
    __syncthreads();
#pragma unroll
    for (int i = 0; i < 2; ++i) {
      int idx = t + 256 * i;
      int tok = idx >> 5, f4 = (idx & 31) * 4;
      *(f32x4*)&Cl[tok][f4] =
          *(const f32x4*)&ctx[(size_t)(tt * 16 + tok) * HID + kt * 128 + f4];
    }
#pragma unroll
    for (int i = 0; i < 8; ++i) {
      int idx = t + 256 * i;
      int r = idx >> 4, f4 = (idx & 15) * 4;
      *(f32x4*)&Wl[r][f4] = *(const f32x4*)&W2[(size_t)(kt * 128 + r) * 64 + f4];
    }
    __syncthreads();
#pragma unroll 8
    for (int c4 = 0; c4 < 128; c4 += 4) {
      f32x4 x0 = *(const f32x4*)&Cl[tokg * 2][c4];
      f32x4 x1 = *(const f32x4*)&Cl[tokg * 2 + 1][c4];
#pragma unroll
      for (int j = 0; j < 4; ++j) {
        float w0 = Wl[c4 + j][colg * 2];
        float w1 = Wl[c4 + j][colg * 2 + 1];
        acc[0][0] += x0[j] * w0;
        acc[0][1] += x0[j] * w1;
        acc[1][0] += x1[j] * w0;
        acc[1][1] += x1[j] * w1;
      }
    }
  }
#pragma unroll
  for (int i = 0; i < 2; ++i)
#pragma unroll
    for (int j = 0; j < 2; ++j) {
      int token = tt * 16 + tokg * 2 + i;
      int col = colg * 2 + j;
      float v = acc[i][j] + b2[col];
      float g = 0.5f * v * (1.0f + erff(v * 0.70710678118654752f));
      out[(size_t)token * 64 + col] = g;
    }
}

// ---------------------------------------------------------------------------
extern "C" void kernel_launch(void* const* d_in, const int* in_sizes, int n_in,
                              void* d_out, int out_size, void* d_ws, size_t ws_size,
                              hipStream_t stream) {
  const float* X = (const float*)d_in[0];      // [4,2048,64]
  const float* qkv_w = (const float*)d_in[1];  // [64,3072]
  const float* qkv_b = (const float*)d_in[2];  // [3072]
  const float* out_w = (const float*)d_in[3];  // [1024,64]
  const float* out_b = (const float*)d_in[4];  // [64]
  float* out = (float*)d_out;

  const size_t NE = (size_t)B_ * H_ * N_ * D_;  // 8388608 elems per array
  unsigned short* ws16 = (unsigned short*)d_ws;
  unsigned short* Qhi = ws16 + 0 * NE;
  unsigned short* Qlo = ws16 + 1 * NE;
  unsigned short* Khi = ws16 + 2 * NE;
  unsigned short* Klo = ws16 + 3 * NE;
  unsigned short* Vhi = ws16 + 4 * NE;
  unsigned short* Vlo = ws16 + 5 * NE;
  float* ctx = (float*)(ws16 + 6 * NE);  // [8192][1024] fp32

  qkv_kernel<<<dim3(24, 256), 256, 0, stream>>>(X, qkv_w, qkv_b, Qhi, Qlo, Khi,
                                                Klo, Vhi, Vlo);
  attn_kernel<<<dim3(N_ / 128, H_, B_), 256, 0, stream>>>(Qhi, Qlo, Khi, Klo,
                                                          Vhi, Vlo, ctx);
  out_kernel<<<512, 256, 0, stream>>>(ctx, out_w, out_b, out);
}